// Round 15
// baseline (375.346 us; speedup 1.0000x reference)
//
#include <hip/hip_runtime.h>
#include <hip/hip_bf16.h>

#define LOG2E 1.4426950408889634f

typedef short bf16x8 __attribute__((ext_vector_type(8)));
typedef float f32x4  __attribute__((ext_vector_type(4)));

// ---------------- workspace layout ----------------
#define OFF_BPf  16
#define OFF_SRWf (OFF_BPf + 384)
#define OFF_SRBf (OFF_SRWf + 1536)
#define OFF_GAf  (OFF_SRBf + 384)
#define OFF_BEf  (OFF_GAf + 384)
#define OFF_MUf  (OFF_BEf + 384)
#define OFF_VAf  (OFF_MUf + 384)     // ends at float 3856 = short 7712
#define U_XB 7712
#define U_WQ (U_XB + 6291456)
#define U_WK (U_WQ + 147456)
#define U_WV (U_WK + 147456)
#define U_WP (U_WV + 147456)
#define U_XK (U_WP + 147456)
#define U_QB (U_XK + 1572864)
#define U_KB (U_QB + 6291456)
#define U_VT (U_KB + 1572864)   // V transposed: [b*8+h][48][1024]
#define U_OB (U_VT + 1572864)   // attention output [b,n,384]

static __device__ __forceinline__ float bfu(unsigned short u){ return __uint_as_float(((unsigned)u) << 16); }
static __device__ __forceinline__ float bf_lo(unsigned v){ return __uint_as_float(v << 16); }
static __device__ __forceinline__ float bf_hi(unsigned v){ return __uint_as_float(v & 0xFFFF0000u); }
static __device__ __forceinline__ unsigned short f2bf(float f){
  unsigned u = __float_as_uint(f);
  u += 0x7FFFu + ((u >> 16) & 1u);      // RNE
  return (unsigned short)(u >> 16);
}
// hardware packed fp32->bf16x2 (v_cvt_pk_bf16_f32, RNE)
static __device__ __forceinline__ unsigned pkcvt(float a, float b){
  float2 f; f.x = a; f.y = b;
  __hip_bfloat162 h = __float22bfloat162_rn(f);
  union { __hip_bfloat162 h2; unsigned u; } cv; cv.h2 = h; return cv.u;
}
static __device__ __forceinline__ unsigned pk2bf(float a, float b){
  return pkcvt(a, b);
}
// raw v_exp_f32 (libm exp2f carries subnormal-range fixup we never need: |x| < 16 here)
static __device__ __forceinline__ float fast_exp2(float x){ return __builtin_amdgcn_exp2f(x); }
// async global->LDS, 16 B per lane; LDS dest = wave-uniform base + lane*16
static __device__ __forceinline__ void gld_lds16(const void* g, void* l){
  __builtin_amdgcn_global_load_lds((const __attribute__((address_space(1))) void*)g,
                                   (__attribute__((address_space(3))) void*)l, 16, 0, 0);
}
// dual-dtype scalar read of a raw param array (bf16-packed or fp32)
static __device__ __forceinline__ float ldp(const void* p, int i, bool bf){
  return bf ? bfu(((const unsigned short*)p)[i]) : ((const float*)p)[i];
}
// 8 fp32 -> 4 packed bf16 words (same RNE as convert path: bit-identical)
static __device__ __forceinline__ void cv8(unsigned* dst, const float* s){
  float4 a = *(const float4*)s, b = *(const float4*)(s + 4);
  dst[0] = pkcvt(a.x, a.y); dst[1] = pkcvt(a.z, a.w);
  dst[2] = pkcvt(b.x, b.y); dst[3] = pkcvt(b.z, b.w);
}

// ---------------- canonicalize helpers (vectorized x8) ----------------
static __device__ __forceinline__ void cp8_bf(unsigned short* dst, const void* src, int off, bool bf){
  if (bf) { *(uint4*)dst = *(const uint4*)((const unsigned short*)src + off); }
  else {
    const float* s = (const float*)src + off;
    float4 a = *(const float4*)s, b = *(const float4*)(s + 4);
    uint4 o; o.x = pk2bf(a.x, a.y); o.y = pk2bf(a.z, a.w);
    o.z = pk2bf(b.x, b.y); o.w = pk2bf(b.z, b.w);
    *(uint4*)dst = o;
  }
}
static __device__ __forceinline__ void cp8_f(float* dst, const void* src, int off, bool bf){
  if (bf) {
    const unsigned short* s = (const unsigned short*)src + off;
    uint4 w = *(const uint4*)s;
    float4 a, b;
    a.x = bf_lo(w.x); a.y = bf_hi(w.x); a.z = bf_lo(w.y); a.w = bf_hi(w.y);
    b.x = bf_lo(w.z); b.y = bf_hi(w.z); b.z = bf_lo(w.w); b.w = bf_hi(w.w);
    *(float4*)dst = a; *(float4*)(dst + 4) = b;
  } else {
    const float* s = (const float*)src + off;
    *(float4*)dst = *(const float4*)s;
    *(float4*)(dst + 4) = *(const float4*)(s + 4);
  }
}

// ---------------- fused prep: self-detect dtype + canonicalize + sr_bn (r12) ----------------
// 6 -> 4 kernel launches: per-iteration dispatch IDs show ~23 dispatches/iter
// (6 ours + ~17 harness resets) — launch chain is a real cost. Every block
// self-detects bf16 from x[0..63] (L2 broadcast). sr_bn-role blocks
// (blockIdx >= 3363) read RAW x + raw conv/BN params (converting with the same
// pkcvt RNE -> bit-identical to the old two-pass path), so no cross-block
// dependency exists within this launch. Block 0 publishes flag for attn/gemm.
__global__ __launch_bounds__(256) void prep_all(
    const void* x, const void* wq, const void* wk, const void* wv, const void* wp,
    const void* bp, const void* srw, const void* srb, const void* ga, const void* be,
    const void* mu, const void* va, float* ws, unsigned short* __restrict__ xkb){
  __shared__ int sflag;
  {
    const unsigned* xraw = (const unsigned*)x;
    if (threadIdx.x < 64) {
      unsigned w = xraw[threadIdx.x];
      unsigned e = (w >> 7) & 0xFFu;
      unsigned long long m = __ballot(e >= 118u && e <= 137u);
      if (threadIdx.x == 0) sflag = (__popcll(m) >= 40) ? 1 : 0;
    }
    __syncthreads();
  }
  const bool bf = sflag != 0;
  unsigned short* u = (unsigned short*)ws;
  if (blockIdx.x == 0 && threadIdx.x == 0) ((int*)ws)[0] = bf ? 1 : 0;  // for attn/gemm_out

  if (blockIdx.x < 3363) {
    // -------- canonicalize region (old convert_all) --------
    int g = blockIdx.x * 256 + threadIdx.x;
    if (g < 786432) { cp8_bf(u + U_XB + g*8, x,  g*8, bf); return; }  g -= 786432;
    if (g < 18432)  { cp8_bf(u + U_WQ + g*8, wq, g*8, bf); return; }  g -= 18432;
    if (g < 18432)  { cp8_bf(u + U_WK + g*8, wk, g*8, bf); return; }  g -= 18432;
    if (g < 18432)  { cp8_bf(u + U_WV + g*8, wv, g*8, bf); return; }  g -= 18432;
    if (g < 18432)  { cp8_bf(u + U_WP + g*8, wp, g*8, bf); return; }  g -= 18432;
    if (g < 192)    { cp8_f(ws + OFF_SRWf + g*8, srw, g*8, bf); return; } g -= 192;
    if (g < 48)     { cp8_f(ws + OFF_BPf  + g*8, bp,  g*8, bf); return; } g -= 48;
    if (g < 48)     { cp8_f(ws + OFF_SRBf + g*8, srb, g*8, bf); return; } g -= 48;
    if (g < 48)     { cp8_f(ws + OFF_GAf  + g*8, ga,  g*8, bf); return; } g -= 48;
    if (g < 48)     { cp8_f(ws + OFF_BEf  + g*8, be,  g*8, bf); return; } g -= 48;
    if (g < 48)     { cp8_f(ws + OFF_MUf  + g*8, mu,  g*8, bf); return; } g -= 48;
    if (g < 48)     { cp8_f(ws + OFF_VAf  + g*8, va,  g*8, bf); }
    return;
  }

  // -------- sr_bn region: depthwise conv 2x2 s2 + BN(eval), reads RAW inputs --------
  int idx = (blockIdx.x - 3363) * 256 + threadIdx.x;   // 196,608 = 4*1024*48
  int c8 = idx % 48;
  int nk = (idx / 48) & 1023;
  int b  = idx / (48 * 1024);
  int i = nk >> 5, j = nk & 31;
  int c0 = c8 * 8;
  size_t base = ((size_t)(b*4096 + i*128 + j*2))*384 + c0;
  unsigned aw[4], bw[4], cw[4], dw[4];
  if (bf) {
    const unsigned short* xp = (const unsigned short*)x + base;
    *(uint4*)aw = *(const uint4*)(xp);
    *(uint4*)bw = *(const uint4*)(xp + 384);
    *(uint4*)cw = *(const uint4*)(xp + 64*384);
    *(uint4*)dw = *(const uint4*)(xp + 65*384);
  } else {
    const float* xp = (const float*)x + base;
    cv8(aw, xp);
    cv8(bw, xp + 384);
    cv8(cw, xp + 64*384);
    cv8(dw, xp + 65*384);
  }
  unsigned out[4];
  #pragma unroll
  for (int k2 = 0; k2 < 4; ++k2) {
    float r2[2];
    #pragma unroll
    for (int half = 0; half < 2; ++half) {
      int k = k2*2 + half;
      int c = c0 + k;
      float xa = half ? bf_hi(aw[k2]) : bf_lo(aw[k2]);
      float xbv = half ? bf_hi(bw[k2]) : bf_lo(bw[k2]);
      float xc = half ? bf_hi(cw[k2]) : bf_lo(cw[k2]);
      float xd = half ? bf_hi(dw[k2]) : bf_lo(dw[k2]);
      float acc = xa*ldp(srw, c*4, bf) + xbv*ldp(srw, c*4+1, bf)
                + xc*ldp(srw, c*4+2, bf) + xd*ldp(srw, c*4+3, bf);
      float inv = rsqrtf(ldp(va, c, bf) + 1e-5f) * ldp(ga, c, bf);
      r2[half] = (acc + ldp(srb, c, bf) - ldp(mu, c, bf)) * inv + ldp(be, c, bf);
    }
    out[k2] = pkcvt(r2[0], r2[1]);
  }
  *(uint4*)(xkb + (size_t)idx*8) = *(uint4*)out;
}

// ---------------- merged Q/K/V projection, 8 waves (r7-measured config) ----------------
__global__ __launch_bounds__(512) void proj_qkv(unsigned short* __restrict__ u){
  int z, by;
  if (blockIdx.y < 128)      { z = 0; by = blockIdx.y; }
  else if (blockIdx.y < 160) { z = 1; by = blockIdx.y - 128; }
  else                       { z = 2; by = blockIdx.y - 160; }
  const unsigned short* A = u + ((z == 0) ? U_XB : U_XK);
  const unsigned short* W = u + ((z == 0) ? U_WQ : (z == 1) ? U_WK : U_WV);

  __shared__ unsigned short As[128][40];
  __shared__ unsigned short Ws[128][40];
  const int tid = threadIdx.x;
  const int wave = tid >> 6, lane = tid & 63, lg = lane >> 4, ln = lane & 15;
  const int m0 = by * 128, n0 = blockIdx.x * 128;
  const int wm = (wave >> 2) * 64, wn = (wave & 3) * 32;
  f32x4 acc[4][2];
  #pragma unroll
  for (int i = 0; i < 4; ++i)
    #pragma unroll
    for (int j = 0; j < 2; ++j) acc[i][j] = (f32x4){0.f,0.f,0.f,0.f};

  const int arow = tid >> 2, acol = (tid & 3) * 8;
  for (int kt = 0; kt < 384; kt += 32) {
    uint4 a0 = *(const uint4*)&A[(size_t)(m0+arow)*384 + kt + acol];
    uint4 w0 = *(const uint4*)&W[(size_t)(n0+arow)*384 + kt + acol];
    __syncthreads();
    *(uint4*)&As[arow][acol] = a0;
    *(uint4*)&Ws[arow][acol] = w0;
    __syncthreads();
    bf16x8 af[4], wf[2];
    #pragma unroll
    for (int mi = 0; mi < 4; ++mi) af[mi] = *(const bf16x8*)&As[wm + mi*16 + ln][lg*8];
    #pragma unroll
    for (int ni = 0; ni < 2; ++ni) wf[ni] = *(const bf16x8*)&Ws[wn + ni*16 + ln][lg*8];
    #pragma unroll
    for (int mi = 0; mi < 4; ++mi)
      #pragma unroll
      for (int ni = 0; ni < 2; ++ni)
        acc[mi][ni] = __builtin_amdgcn_mfma_f32_16x16x32_bf16(af[mi], wf[ni], acc[mi][ni], 0, 0, 0);
  }

  unsigned short* outQ = u + U_QB;
  unsigned short* outK = u + U_KB;
  unsigned short* outV = u + U_VT;
  #pragma unroll
  for (int mi = 0; mi < 4; ++mi)
    #pragma unroll
    for (int ni = 0; ni < 2; ++ni) {
      int gcol = n0 + wn + ni*16 + ln;
      if (z == 2) {
        int grow0 = m0 + wm + mi*16 + lg*4;
        int hh = gcol / 48, d = gcol - hh*48;
        int bb = grow0 >> 10, mk = grow0 & 1023;
        uint2 st; st.x = pkcvt(acc[mi][ni][0], acc[mi][ni][1]);
        st.y = pkcvt(acc[mi][ni][2], acc[mi][ni][3]);
        *(uint2*)&outV[((size_t)((bb*8 + hh)*48 + d))*1024 + mk] = st;
      } else {
        unsigned short* dst = (z == 0) ? outQ : outK;
        #pragma unroll
        for (int r = 0; r < 4; ++r) {
          int grow = m0 + wm + mi*16 + lg*4 + r;
          dst[(size_t)grow*384 + gcol] = f2bf(acc[mi][ni][r]);
        }
      }
    }
}

// ---------------- out-projection GEMM + bias, 8 waves (r7-measured config) ----------------
__global__ __launch_bounds__(512) void gemm_out(const unsigned short* __restrict__ A,
    const unsigned short* __restrict__ W, const float* __restrict__ bias,
    void* __restrict__ out, const int* __restrict__ flag){
  __shared__ unsigned short As[128][40];
  __shared__ unsigned short Ws[128][40];
  const int tid = threadIdx.x;
  const int wave = tid >> 6, lane = tid & 63, lg = lane >> 4, ln = lane & 15;
  const int m0 = blockIdx.y * 128, n0 = blockIdx.x * 128;
  const int wm = (wave >> 2) * 64, wn = (wave & 3) * 32;
  f32x4 acc[4][2];
  #pragma unroll
  for (int i = 0; i < 4; ++i)
    #pragma unroll
    for (int j = 0; j < 2; ++j) acc[i][j] = (f32x4){0.f,0.f,0.f,0.f};

  const int arow = tid >> 2, acol = (tid & 3) * 8;
  for (int kt = 0; kt < 384; kt += 32) {
    uint4 a0 = *(const uint4*)&A[(size_t)(m0+arow)*384 + kt + acol];
    uint4 w0 = *(const uint4*)&W[(size_t)(n0+arow)*384 + kt + acol];
    __syncthreads();
    *(uint4*)&As[arow][acol] = a0;
    *(uint4*)&Ws[arow][acol] = w0;
    __syncthreads();
    bf16x8 af[4], wf[2];
    #pragma unroll
    for (int mi = 0; mi < 4; ++mi) af[mi] = *(const bf16x8*)&As[wm + mi*16 + ln][lg*8];
    #pragma unroll
    for (int ni = 0; ni < 2; ++ni) wf[ni] = *(const bf16x8*)&Ws[wn + ni*16 + ln][lg*8];
    #pragma unroll
    for (int mi = 0; mi < 4; ++mi)
      #pragma unroll
      for (int ni = 0; ni < 2; ++ni)
        acc[mi][ni] = __builtin_amdgcn_mfma_f32_16x16x32_bf16(af[mi], wf[ni], acc[mi][ni], 0, 0, 0);
  }

  const bool bff = (*flag != 0);
  #pragma unroll
  for (int mi = 0; mi < 4; ++mi)
    #pragma unroll
    for (int ni = 0; ni < 2; ++ni)
      #pragma unroll
      for (int r = 0; r < 4; ++r) {
        int grow = m0 + wm + mi*16 + lg*4 + r;
        int gcol = n0 + wn + ni*16 + ln;
        float v = acc[mi][ni][r] + bias[gcol];
        if (bff) ((unsigned short*)out)[(size_t)grow*384 + gcol] = f2bf(v);
        else     ((float*)out)[(size_t)grow*384 + gcol] = v;
      }
}

// ---------------- MFMA flash attention (r7-measured: 124.7 us; FROZEN) ----------------
// grid (128, 8). 256 thr = 4 waves x 32 q-rows. K dbuf via global_load_lds;
// V single-buffered; Ps qt-seq [4][16][64] XOR-swizzled. rel loaded at tile top.
// LESSONS: (r1,r3,r8) allocator pins 64 VGPR and SPILLS any cross-phase rel
// pipelining state (WRITE_SIZE tripwire). (r6) kv-split regressed. Stable at
// ~125 us across 6 variants.
__global__ __launch_bounds__(256, 4) void attn_mfma(const unsigned short* __restrict__ qb,
    const unsigned short* __restrict__ kb, const unsigned short* __restrict__ vt,
    const void* __restrict__ rel, const int* __restrict__ flag,
    unsigned short* __restrict__ ob){
  __shared__ __align__(16) unsigned short Kbuf[2][6*512];
  __shared__ __align__(16) unsigned short Vbuf[8*384];
  __shared__ __align__(16) unsigned short Ps[4][16][64];   // one q-subtile, XOR-swizzled
  __shared__ float Ls[4][32];                              // lsum transpose
  const int x = blockIdx.x;
  const int b = x >> 5, nb = x & 31, h = blockIdx.y;
  const int tid = threadIdx.x, wave = tid >> 6, lane = tid & 63;
  const int lg = lane >> 4, ln = lane & 15;
  const int qrow0 = nb * 128 + wave * 32;
  const bool bfm = (*flag != 0);
  const float SCL = 0.14433756729740643f * LOG2E;

  // Q fragments (B-operand; pad 48->64 with 0)
  bf16x8 qf0[2], qf1[2];
  #pragma unroll
  for (int qt = 0; qt < 2; ++qt) {
    const unsigned short* qp = qb + ((size_t)(b*4096 + qrow0 + qt*16 + ln))*384 + h*48;
    qf0[qt] = *(const bf16x8*)(qp + lg*8);
    bf16x8 z = {0,0,0,0,0,0,0,0};
    if (lg < 2) z = *(const bf16x8*)(qp + 32 + lg*8);
    qf1[qt] = z;
  }

  f32x4 o[2][3];
  #pragma unroll
  for (int qt = 0; qt < 2; ++qt) { o[qt][0] = (f32x4){0.f,0.f,0.f,0.f}; o[qt][1] = o[qt][0]; o[qt][2] = o[qt][0]; }
  float lsum[2] = {0.f, 0.f};

  const float* relf = (const float*)rel;
  const unsigned short* relh = (const unsigned short*)rel;
  const size_t rbase = ((size_t)(h*4096 + qrow0 + ln)) * 1024;
  const size_t kbase = (size_t)(b*1024) * 384 + (size_t)h*48;   // shorts
  const size_t vbase = ((size_t)(b*8 + h)) * 48 * 1024;          // shorts

  const unsigned swz = (unsigned)((ln & 7) << 4);
  char* psrow = (char*)&Ps[wave][ln][0];

  // staging assignments: 6 K-insts + 6 V-insts split 3/wave
  const int jk1 = wave;
  const int jk2 = 4 + wave;              // valid for wave<2
  const int jv1 = wave;
  const int jv2 = 2 + wave;              // valid for wave>=2
  int s1i = jv1*64 + lane;  int c1 = s1i/48, d1 = s1i - 48*c1;
  size_t vg1 = vbase + (size_t)d1*1024 + c1*8;
  int s2i = jv2*64 + lane;  int c2 = s2i/48, d2 = s2i - 48*c2;
  size_t vg2 = vbase + (size_t)d2*1024 + c2*8;

  // prologue: stage K(0) into buf 0
  gld_lds16(kb + kbase + (size_t)lane*384 + jk1*8, &Kbuf[0][jk1*512]);
  if (wave < 2) gld_lds16(kb + kbase + (size_t)lane*384 + jk2*8, &Kbuf[0][jk2*512]);

  #pragma unroll 1
  for (int t = 0; t < 16; ++t) {
    const int cbuf = t & 1, nbuf = cbuf ^ 1;
    __syncthreads();     // A: drain-free; protects Vbuf/Kbuf[nbuf]

    // rel prefetch FIRST (oldest in vmcnt queue); consumed at sm(q0)/sm(q1)
    uint2 rr[2][4];
    if (bfm) {
      #pragma unroll
      for (int qt = 0; qt < 2; ++qt)
        #pragma unroll
        for (int mt = 0; mt < 4; ++mt)
          rr[qt][mt] = *(const uint2*)(relh + rbase + (size_t)qt*16384 + t*64 + mt*16 + lg*4);
    } else {
      #pragma unroll
      for (int qt = 0; qt < 2; ++qt)
        #pragma unroll
        for (int mt = 0; mt < 4; ++mt) {
          float4 q_ = *(const float4*)(relf + rbase + (size_t)qt*16384 + t*64 + mt*16 + lg*4);
          rr[qt][mt].x = pkcvt(q_.x, q_.y); rr[qt][mt].y = pkcvt(q_.z, q_.w);
        }
    }

    // async staging: V(t) and K(t+1)
    gld_lds16(vt + vg1 + t*64, &Vbuf[jv1*512]);
    if (wave >= 2) gld_lds16(vt + vg2 + t*64, &Vbuf[jv2*512]);
    const int T = (t + 1 < 16) ? t + 1 : 15;
    gld_lds16(kb + kbase + (size_t)T*24576 + (size_t)lane*384 + jk1*8, &Kbuf[nbuf][jk1*512]);
    if (wave < 2) gld_lds16(kb + kbase + (size_t)T*24576 + (size_t)lane*384 + jk2*8, &Kbuf[nbuf][jk2*512]);

    // ---- S-phase qt0: 8 MFMAs ----
    f32x4 s0[4];
    #pragma unroll
    for (int mt = 0; mt < 4; ++mt) {
      bf16x8 k0 = *(const bf16x8*)&Kbuf[cbuf][lg*512 + (mt*16 + ln)*8];
      bf16x8 k1 = {0,0,0,0,0,0,0,0};
      if (lg < 2) k1 = *(const bf16x8*)&Kbuf[cbuf][(4 + lg)*512 + (mt*16 + ln)*8];
      s0[mt] = __builtin_amdgcn_mfma_f32_16x16x32_bf16(k0, qf0[0], (f32x4){0.f,0.f,0.f,0.f}, 0, 0, 0);
      s0[mt] = __builtin_amdgcn_mfma_f32_16x16x32_bf16(k1, qf1[0], s0[mt], 0, 0, 0);
    }
    // ---- softmax qt0 -> Ps (swizzled) ----
    {
      float lacc = 0.f;
      #pragma unroll
      for (int mt = 0; mt < 4; ++mt) {
        float r0 = bf_lo(rr[0][mt].x), r1 = bf_hi(rr[0][mt].x);
        float r2 = bf_lo(rr[0][mt].y), r3 = bf_hi(rr[0][mt].y);
        float p0 = fast_exp2(fmaf(s0[mt][0], SCL, r0 * LOG2E));
        float p1 = fast_exp2(fmaf(s0[mt][1], SCL, r1 * LOG2E));
        float p2 = fast_exp2(fmaf(s0[mt][2], SCL, r2 * LOG2E));
        float p3 = fast_exp2(fmaf(s0[mt][3], SCL, r3 * LOG2E));
        lacc += (p0 + p1) + (p2 + p3);
        uint2 w; w.x = pkcvt(p0, p1); w.y = pkcvt(p2, p3);
        *(uint2*)(psrow + (((unsigned)(mt*32 + lg*8)) ^ swz)) = w;
      }
      lsum[0] += lacc;
    }

    __syncthreads();     // B: vmcnt(0) drain -> V(t)/K(t+1) in LDS (covered by S0+sm0)

    // ---- PV qt0: 6 MFMAs ----
    #pragma unroll
    for (int ks = 0; ks < 2; ++ks) {
      bf16x8 vf[3];
      #pragma unroll
      for (int nd = 0; nd < 3; ++nd)
        vf[nd] = *(const bf16x8*)&Vbuf[(ks*4 + lg)*384 + (nd*16 + ln)*8];
      bf16x8 pa = *(const bf16x8*)(psrow + (((unsigned)(ks*64 + lg*16)) ^ swz));
      #pragma unroll
      for (int nd = 0; nd < 3; ++nd)
        o[0][nd] = __builtin_amdgcn_mfma_f32_16x16x32_bf16(pa, vf[nd], o[0][nd], 0, 0, 0);
    }

    // ---- S-phase qt1: 8 MFMAs (Kbuf[cbuf] still valid) ----
    f32x4 s1[4];
    #pragma unroll
    for (int mt = 0; mt < 4; ++mt) {
      bf16x8 k0 = *(const bf16x8*)&Kbuf[cbuf][lg*512 + (mt*16 + ln)*8];
      bf16x8 k1 = {0,0,0,0,0,0,0,0};
      if (lg < 2) k1 = *(const bf16x8*)&Kbuf[cbuf][(4 + lg)*512 + (mt*16 + ln)*8];
      s1[mt] = __builtin_amdgcn_mfma_f32_16x16x32_bf16(k0, qf0[1], (f32x4){0.f,0.f,0.f,0.f}, 0, 0, 0);
      s1[mt] = __builtin_amdgcn_mfma_f32_16x16x32_bf16(k1, qf1[1], s1[mt], 0, 0, 0);
    }
    // ---- softmax qt1 -> Ps (reuse; in-order per-wave DS makes this safe) ----
    {
      float lacc = 0.f;
      #pragma unroll
      for (int mt = 0; mt < 4; ++mt) {
        float r0 = bf_lo(rr[1][mt].x), r1 = bf_hi(rr[1][mt].x);
        float r2 = bf_lo(rr[1][mt].y), r3 = bf_hi(rr[1][mt].y);
        float p0 = fast_exp2(fmaf(s1[mt][0], SCL, r0 * LOG2E));
        float p1 = fast_exp2(fmaf(s1[mt][1], SCL, r1 * LOG2E));
        float p2 = fast_exp2(fmaf(s1[mt][2], SCL, r2 * LOG2E));
        float p3 = fast_exp2(fmaf(s1[mt][3], SCL, r3 * LOG2E));
        lacc += (p0 + p1) + (p2 + p3);
        uint2 w; w.x = pkcvt(p0, p1); w.y = pkcvt(p2, p3);
        *(uint2*)(psrow + (((unsigned)(mt*32 + lg*8)) ^ swz)) = w;
      }
      lsum[1] += lacc;
    }
    // ---- PV qt1: 6 MFMAs ----
    #pragma unroll
    for (int ks = 0; ks < 2; ++ks) {
      bf16x8 vf[3];
      #pragma unroll
      for (int nd = 0; nd < 3; ++nd)
        vf[nd] = *(const bf16x8*)&Vbuf[(ks*4 + lg)*384 + (nd*16 + ln)*8];
      bf16x8 pa = *(const bf16x8*)(psrow + (((unsigned)(ks*64 + lg*16)) ^ swz));
      #pragma unroll
      for (int nd = 0; nd < 3; ++nd)
        o[1][nd] = __builtin_amdgcn_mfma_f32_16x16x32_bf16(pa, vf[nd], o[1][nd], 0, 0, 0);
    }
  }

  // l: reduce across the 4 lg-lanes of each q-row; transpose via Ls
  #pragma unroll
  for (int qt = 0; qt < 2; ++qt) {
    lsum[qt] += __shfl_xor(lsum[qt], 16, 64);
    lsum[qt] += __shfl_xor(lsum[qt], 32, 64);
    if (lg == 0) Ls[wave][qt*16 + ln] = lsum[qt];
  }
  #pragma unroll
  for (int qt = 0; qt < 2; ++qt)
    #pragma unroll
    for (int r = 0; r < 4; ++r) {
      float l = Ls[wave][qt*16 + lg*4 + r];
      float linv = 1.0f / l;
      size_t rowb = ((size_t)(b*4096 + qrow0 + qt*16 + lg*4 + r))*384 + h*48 + ln;
      #pragma unroll
      for (int nd = 0; nd < 3; ++nd)
        ob[rowb + nd*16] = f2bf(o[qt][nd][r] * linv);
    }
}

extern "C" void kernel_launch(void* const* d_in, const int* in_sizes, int n_in,
                              void* d_out, int out_size, void* d_ws, size_t ws_size,
                              hipStream_t stream) {
  // d_in: 0=x 1=relative_pos 2=H 3=W 4=Wq 5=Wk 6=Wv 7=Wp 8=bp 9=sr_w 10=sr_b
  //       11=bn_gamma 12=bn_beta 13=bn_mean 14=bn_var
  float* ws = (float*)d_ws;
  int* flag = (int*)d_ws;
  unsigned short* u = (unsigned short*)d_ws;

  prep_all<<<4131, 256, 0, stream>>>(d_in[0], d_in[4], d_in[5], d_in[6], d_in[7],
      d_in[8], d_in[9], d_in[10], d_in[11], d_in[12], d_in[13], d_in[14], ws, u + U_XK);
  proj_qkv<<<dim3(3, 192), 512, 0, stream>>>(u);
  attn_mfma<<<dim3(128, 8), 256, 0, stream>>>(u + U_QB, u + U_KB, u + U_VT, d_in[1], flag, u + U_OB);
  gemm_out<<<dim3(3, 128), 512, 0, stream>>>(u + U_OB, u + U_WP, ws + OFF_BPf, d_out, flag);
}

// Round 16
// 349.871 us; speedup vs baseline: 1.0728x; 1.0728x over previous
//
#include <hip/hip_runtime.h>
#include <hip/hip_bf16.h>

#define LOG2E 1.4426950408889634f

typedef short bf16x8 __attribute__((ext_vector_type(8)));
typedef float f32x4  __attribute__((ext_vector_type(4)));

// ---------------- workspace layout ----------------
#define OFF_BPf  16
#define OFF_SRWf (OFF_BPf + 384)
#define OFF_SRBf (OFF_SRWf + 1536)
#define OFF_GAf  (OFF_SRBf + 384)
#define OFF_BEf  (OFF_GAf + 384)
#define OFF_MUf  (OFF_BEf + 384)
#define OFF_VAf  (OFF_MUf + 384)     // ends at float 3856 = short 7712
#define U_XB 7712
#define U_WQ (U_XB + 6291456)
#define U_WK (U_WQ + 147456)
#define U_WV (U_WK + 147456)
#define U_WP (U_WV + 147456)
#define U_XK (U_WP + 147456)
#define U_QB (U_XK + 1572864)
#define U_KB (U_QB + 6291456)
#define U_VT (U_KB + 1572864)   // V transposed: [b*8+h][48][1024]
#define U_OB (U_VT + 1572864)   // attention output [b,n,384]

static __device__ __forceinline__ float bfu(unsigned short u){ return __uint_as_float(((unsigned)u) << 16); }
static __device__ __forceinline__ float bf_lo(unsigned v){ return __uint_as_float(v << 16); }
static __device__ __forceinline__ float bf_hi(unsigned v){ return __uint_as_float(v & 0xFFFF0000u); }
static __device__ __forceinline__ unsigned short f2bf(float f){
  unsigned u = __float_as_uint(f);
  u += 0x7FFFu + ((u >> 16) & 1u);      // RNE
  return (unsigned short)(u >> 16);
}
// hardware packed fp32->bf16x2 (v_cvt_pk_bf16_f32, RNE)
static __device__ __forceinline__ unsigned pkcvt(float a, float b){
  float2 f; f.x = a; f.y = b;
  __hip_bfloat162 h = __float22bfloat162_rn(f);
  union { __hip_bfloat162 h2; unsigned u; } cv; cv.h2 = h; return cv.u;
}
static __device__ __forceinline__ unsigned pk2bf(float a, float b){
  return pkcvt(a, b);
}
// raw v_exp_f32 (libm exp2f carries subnormal-range fixup we never need: |x| < 16 here)
// verified: absmax unchanged vs libm (rounds 1-15)
static __device__ __forceinline__ float fast_exp2(float x){ return __builtin_amdgcn_exp2f(x); }
// async global->LDS, 16 B per lane; LDS dest = wave-uniform base + lane*16
static __device__ __forceinline__ void gld_lds16(const void* g, void* l){
  __builtin_amdgcn_global_load_lds((const __attribute__((address_space(1))) void*)g,
                                   (__attribute__((address_space(3))) void*)l, 16, 0, 0);
}

// ---------------- dtype detection (bf16-packed vs fp32 inputs) ----------------
__global__ void detect_bf16(const unsigned* __restrict__ xraw, int* __restrict__ flag){
  unsigned w = xraw[threadIdx.x];
  unsigned e = (w >> 7) & 0xFFu;
  unsigned long long m = __ballot(e >= 118u && e <= 137u);
  if (threadIdx.x == 0) *flag = (__popcll(m) >= 40) ? 1 : 0;
}

// ---------------- canonicalize inputs (vectorized x8) ----------------
static __device__ __forceinline__ void cp8_bf(unsigned short* dst, const void* src, int off, bool bf){
  if (bf) { *(uint4*)dst = *(const uint4*)((const unsigned short*)src + off); }
  else {
    const float* s = (const float*)src + off;
    float4 a = *(const float4*)s, b = *(const float4*)(s + 4);
    uint4 o; o.x = pk2bf(a.x, a.y); o.y = pk2bf(a.z, a.w);
    o.z = pk2bf(b.x, b.y); o.w = pk2bf(b.z, b.w);
    *(uint4*)dst = o;
  }
}
static __device__ __forceinline__ void cp8_f(float* dst, const void* src, int off, bool bf){
  if (bf) {
    const unsigned short* s = (const unsigned short*)src + off;
    uint4 w = *(const uint4*)s;
    float4 a, b;
    a.x = bf_lo(w.x); a.y = bf_hi(w.x); a.z = bf_lo(w.y); a.w = bf_hi(w.y);
    b.x = bf_lo(w.z); b.y = bf_hi(w.z); b.z = bf_lo(w.w); b.w = bf_hi(w.w);
    *(float4*)dst = a; *(float4*)(dst + 4) = b;
  } else {
    const float* s = (const float*)src + off;
    *(float4*)dst = *(const float4*)s;
    *(float4*)(dst + 4) = *(const float4*)(s + 4);
  }
}

__global__ __launch_bounds__(256) void convert_all(
    const void* x, const void* wq, const void* wk, const void* wv, const void* wp,
    const void* bp, const void* srw, const void* srb, const void* ga, const void* be,
    const void* mu, const void* va, float* ws){
  const bool bf = ((const int*)ws)[0] != 0;
  unsigned short* u = (unsigned short*)ws;
  int g = blockIdx.x * 256 + threadIdx.x;
  if (g < 786432) { cp8_bf(u + U_XB + g*8, x,  g*8, bf); return; }  g -= 786432;
  if (g < 18432)  { cp8_bf(u + U_WQ + g*8, wq, g*8, bf); return; }  g -= 18432;
  if (g < 18432)  { cp8_bf(u + U_WK + g*8, wk, g*8, bf); return; }  g -= 18432;
  if (g < 18432)  { cp8_bf(u + U_WV + g*8, wv, g*8, bf); return; }  g -= 18432;
  if (g < 18432)  { cp8_bf(u + U_WP + g*8, wp, g*8, bf); return; }  g -= 18432;
  if (g < 192)    { cp8_f(ws + OFF_SRWf + g*8, srw, g*8, bf); return; } g -= 192;
  if (g < 48)     { cp8_f(ws + OFF_BPf  + g*8, bp,  g*8, bf); return; } g -= 48;
  if (g < 48)     { cp8_f(ws + OFF_SRBf + g*8, srb, g*8, bf); return; } g -= 48;
  if (g < 48)     { cp8_f(ws + OFF_GAf  + g*8, ga,  g*8, bf); return; } g -= 48;
  if (g < 48)     { cp8_f(ws + OFF_BEf  + g*8, be,  g*8, bf); return; } g -= 48;
  if (g < 48)     { cp8_f(ws + OFF_MUf  + g*8, mu,  g*8, bf); return; } g -= 48;
  if (g < 48)     { cp8_f(ws + OFF_VAf  + g*8, va,  g*8, bf); }
}

// ---------------- depthwise conv 2x2 s2 + BN(eval), vectorized x8 ----------------
__global__ __launch_bounds__(256) void sr_bn(const unsigned short* __restrict__ xb,
    const float* __restrict__ wsf, unsigned short* __restrict__ xkb){
  int idx = blockIdx.x * 256 + threadIdx.x;       // 196,608 = 4*1024*48
  int c8 = idx % 48;
  int nk = (idx / 48) & 1023;
  int b  = idx / (48 * 1024);
  int i = nk >> 5, j = nk & 31;
  int c0 = c8 * 8;
  const unsigned short* xp = xb + ((size_t)(b*4096 + i*128 + j*2))*384 + c0;
  unsigned aw[4], bw[4], cw[4], dw[4];
  *(uint4*)aw = *(const uint4*)(xp);
  *(uint4*)bw = *(const uint4*)(xp + 384);
  *(uint4*)cw = *(const uint4*)(xp + 64*384);
  *(uint4*)dw = *(const uint4*)(xp + 65*384);
  unsigned out[4];
  #pragma unroll
  for (int k2 = 0; k2 < 4; ++k2) {
    float r2[2];
    #pragma unroll
    for (int half = 0; half < 2; ++half) {
      int k = k2*2 + half;
      int c = c0 + k;
      float xa = half ? bf_hi(aw[k2]) : bf_lo(aw[k2]);
      float xbv = half ? bf_hi(bw[k2]) : bf_lo(bw[k2]);
      float xc = half ? bf_hi(cw[k2]) : bf_lo(cw[k2]);
      float xd = half ? bf_hi(dw[k2]) : bf_lo(dw[k2]);
      float acc = xa*wsf[OFF_SRWf+c*4] + xbv*wsf[OFF_SRWf+c*4+1]
                + xc*wsf[OFF_SRWf+c*4+2] + xd*wsf[OFF_SRWf+c*4+3];
      float inv = rsqrtf(wsf[OFF_VAf+c] + 1e-5f) * wsf[OFF_GAf+c];
      r2[half] = (acc + wsf[OFF_SRBf+c] - wsf[OFF_MUf+c]) * inv + wsf[OFF_BEf+c];
    }
    out[k2] = pkcvt(r2[0], r2[1]);
  }
  *(uint4*)(xkb + (size_t)idx*8) = *(uint4*)out;
}

// ---------------- merged Q/K/V projection, 8 waves (r7-measured best) ----------------
__global__ __launch_bounds__(512) void proj_qkv(unsigned short* __restrict__ u){
  int z, by;
  if (blockIdx.y < 128)      { z = 0; by = blockIdx.y; }
  else if (blockIdx.y < 160) { z = 1; by = blockIdx.y - 128; }
  else                       { z = 2; by = blockIdx.y - 160; }
  const unsigned short* A = u + ((z == 0) ? U_XB : U_XK);
  const unsigned short* W = u + ((z == 0) ? U_WQ : (z == 1) ? U_WK : U_WV);

  __shared__ unsigned short As[128][40];
  __shared__ unsigned short Ws[128][40];
  const int tid = threadIdx.x;
  const int wave = tid >> 6, lane = tid & 63, lg = lane >> 4, ln = lane & 15;
  const int m0 = by * 128, n0 = blockIdx.x * 128;
  const int wm = (wave >> 2) * 64, wn = (wave & 3) * 32;
  f32x4 acc[4][2];
  #pragma unroll
  for (int i = 0; i < 4; ++i)
    #pragma unroll
    for (int j = 0; j < 2; ++j) acc[i][j] = (f32x4){0.f,0.f,0.f,0.f};

  const int arow = tid >> 2, acol = (tid & 3) * 8;
  for (int kt = 0; kt < 384; kt += 32) {
    uint4 a0 = *(const uint4*)&A[(size_t)(m0+arow)*384 + kt + acol];
    uint4 w0 = *(const uint4*)&W[(size_t)(n0+arow)*384 + kt + acol];
    __syncthreads();
    *(uint4*)&As[arow][acol] = a0;
    *(uint4*)&Ws[arow][acol] = w0;
    __syncthreads();
    bf16x8 af[4], wf[2];
    #pragma unroll
    for (int mi = 0; mi < 4; ++mi) af[mi] = *(const bf16x8*)&As[wm + mi*16 + ln][lg*8];
    #pragma unroll
    for (int ni = 0; ni < 2; ++ni) wf[ni] = *(const bf16x8*)&Ws[wn + ni*16 + ln][lg*8];
    #pragma unroll
    for (int mi = 0; mi < 4; ++mi)
      #pragma unroll
      for (int ni = 0; ni < 2; ++ni)
        acc[mi][ni] = __builtin_amdgcn_mfma_f32_16x16x32_bf16(af[mi], wf[ni], acc[mi][ni], 0, 0, 0);
  }

  unsigned short* outQ = u + U_QB;
  unsigned short* outK = u + U_KB;
  unsigned short* outV = u + U_VT;
  #pragma unroll
  for (int mi = 0; mi < 4; ++mi)
    #pragma unroll
    for (int ni = 0; ni < 2; ++ni) {
      int gcol = n0 + wn + ni*16 + ln;
      if (z == 2) {
        // V^T packed store: rows r are m-consecutive -> one 8 B store of 4 bf16
        int grow0 = m0 + wm + mi*16 + lg*4;
        int hh = gcol / 48, d = gcol - hh*48;
        int bb = grow0 >> 10, mk = grow0 & 1023;
        uint2 st; st.x = pkcvt(acc[mi][ni][0], acc[mi][ni][1]);
        st.y = pkcvt(acc[mi][ni][2], acc[mi][ni][3]);
        *(uint2*)&outV[((size_t)((bb*8 + hh)*48 + d))*1024 + mk] = st;
      } else {
        unsigned short* dst = (z == 0) ? outQ : outK;
        #pragma unroll
        for (int r = 0; r < 4; ++r) {
          int grow = m0 + wm + mi*16 + lg*4 + r;
          dst[(size_t)grow*384 + gcol] = f2bf(acc[mi][ni][r]);
        }
      }
    }
}

// ---------------- out-projection GEMM + bias, 8 waves (r7-measured best) ----------------
__global__ __launch_bounds__(512) void gemm_out(const unsigned short* __restrict__ A,
    const unsigned short* __restrict__ W, const float* __restrict__ bias,
    void* __restrict__ out, const int* __restrict__ flag){
  __shared__ unsigned short As[128][40];
  __shared__ unsigned short Ws[128][40];
  const int tid = threadIdx.x;
  const int wave = tid >> 6, lane = tid & 63, lg = lane >> 4, ln = lane & 15;
  const int m0 = blockIdx.y * 128, n0 = blockIdx.x * 128;
  const int wm = (wave >> 2) * 64, wn = (wave & 3) * 32;
  f32x4 acc[4][2];
  #pragma unroll
  for (int i = 0; i < 4; ++i)
    #pragma unroll
    for (int j = 0; j < 2; ++j) acc[i][j] = (f32x4){0.f,0.f,0.f,0.f};

  const int arow = tid >> 2, acol = (tid & 3) * 8;
  for (int kt = 0; kt < 384; kt += 32) {
    uint4 a0 = *(const uint4*)&A[(size_t)(m0+arow)*384 + kt + acol];
    uint4 w0 = *(const uint4*)&W[(size_t)(n0+arow)*384 + kt + acol];
    __syncthreads();
    *(uint4*)&As[arow][acol] = a0;
    *(uint4*)&Ws[arow][acol] = w0;
    __syncthreads();
    bf16x8 af[4], wf[2];
    #pragma unroll
    for (int mi = 0; mi < 4; ++mi) af[mi] = *(const bf16x8*)&As[wm + mi*16 + ln][lg*8];
    #pragma unroll
    for (int ni = 0; ni < 2; ++ni) wf[ni] = *(const bf16x8*)&Ws[wn + ni*16 + ln][lg*8];
    #pragma unroll
    for (int mi = 0; mi < 4; ++mi)
      #pragma unroll
      for (int ni = 0; ni < 2; ++ni)
        acc[mi][ni] = __builtin_amdgcn_mfma_f32_16x16x32_bf16(af[mi], wf[ni], acc[mi][ni], 0, 0, 0);
  }

  const bool bff = (*flag != 0);
  #pragma unroll
  for (int mi = 0; mi < 4; ++mi)
    #pragma unroll
    for (int ni = 0; ni < 2; ++ni)
      #pragma unroll
      for (int r = 0; r < 4; ++r) {
        int grow = m0 + wm + mi*16 + lg*4 + r;
        int gcol = n0 + wn + ni*16 + ln;
        float v = acc[mi][ni][r] + bias[gcol];
        if (bff) ((unsigned short*)out)[(size_t)grow*384 + gcol] = f2bf(v);
        else     ((float*)out)[(size_t)grow*384 + gcol] = v;
      }
}

// ---------------- MFMA flash attention (r7-measured: 124.7 us; FROZEN) ----------------
// grid (128, 8). 256 thr = 4 waves x 32 q-rows. K dbuf via global_load_lds;
// V single-buffered; Ps qt-seq [4][16][64] XOR-swizzled. rel loaded at tile top.
// LESSONS: (r1,r3,r8) allocator pins 64 VGPR and SPILLS any cross-phase rel
// pipelining state (WRITE_SIZE tripwire). (r6) kv-split regressed. (r12/r15)
// launch fusion regressed. Stable at ~125 us across 6 variants.
__global__ __launch_bounds__(256, 4) void attn_mfma(const unsigned short* __restrict__ qb,
    const unsigned short* __restrict__ kb, const unsigned short* __restrict__ vt,
    const void* __restrict__ rel, const int* __restrict__ flag,
    unsigned short* __restrict__ ob){
  __shared__ __align__(16) unsigned short Kbuf[2][6*512];
  __shared__ __align__(16) unsigned short Vbuf[8*384];
  __shared__ __align__(16) unsigned short Ps[4][16][64];   // one q-subtile, XOR-swizzled
  __shared__ float Ls[4][32];                              // lsum transpose
  const int x = blockIdx.x;
  const int b = x >> 5, nb = x & 31, h = blockIdx.y;
  const int tid = threadIdx.x, wave = tid >> 6, lane = tid & 63;
  const int lg = lane >> 4, ln = lane & 15;
  const int qrow0 = nb * 128 + wave * 32;
  const bool bfm = (*flag != 0);
  const float SCL = 0.14433756729740643f * LOG2E;

  // Q fragments (B-operand; pad 48->64 with 0)
  bf16x8 qf0[2], qf1[2];
  #pragma unroll
  for (int qt = 0; qt < 2; ++qt) {
    const unsigned short* qp = qb + ((size_t)(b*4096 + qrow0 + qt*16 + ln))*384 + h*48;
    qf0[qt] = *(const bf16x8*)(qp + lg*8);
    bf16x8 z = {0,0,0,0,0,0,0,0};
    if (lg < 2) z = *(const bf16x8*)(qp + 32 + lg*8);
    qf1[qt] = z;
  }

  f32x4 o[2][3];
  #pragma unroll
  for (int qt = 0; qt < 2; ++qt) { o[qt][0] = (f32x4){0.f,0.f,0.f,0.f}; o[qt][1] = o[qt][0]; o[qt][2] = o[qt][0]; }
  float lsum[2] = {0.f, 0.f};

  const float* relf = (const float*)rel;
  const unsigned short* relh = (const unsigned short*)rel;
  const size_t rbase = ((size_t)(h*4096 + qrow0 + ln)) * 1024;
  const size_t kbase = (size_t)(b*1024) * 384 + (size_t)h*48;   // shorts
  const size_t vbase = ((size_t)(b*8 + h)) * 48 * 1024;          // shorts

  const unsigned swz = (unsigned)((ln & 7) << 4);
  char* psrow = (char*)&Ps[wave][ln][0];

  // staging assignments: 6 K-insts + 6 V-insts split 3/wave
  const int jk1 = wave;
  const int jk2 = 4 + wave;              // valid for wave<2
  const int jv1 = wave;
  const int jv2 = 2 + wave;              // valid for wave>=2
  int s1i = jv1*64 + lane;  int c1 = s1i/48, d1 = s1i - 48*c1;
  size_t vg1 = vbase + (size_t)d1*1024 + c1*8;
  int s2i = jv2*64 + lane;  int c2 = s2i/48, d2 = s2i - 48*c2;
  size_t vg2 = vbase + (size_t)d2*1024 + c2*8;

  // prologue: stage K(0) into buf 0
  gld_lds16(kb + kbase + (size_t)lane*384 + jk1*8, &Kbuf[0][jk1*512]);
  if (wave < 2) gld_lds16(kb + kbase + (size_t)lane*384 + jk2*8, &Kbuf[0][jk2*512]);

  #pragma unroll 1
  for (int t = 0; t < 16; ++t) {
    const int cbuf = t & 1, nbuf = cbuf ^ 1;
    __syncthreads();     // A: drain-free; protects Vbuf/Kbuf[nbuf]

    // rel prefetch FIRST (oldest in vmcnt queue); consumed at sm(q0)/sm(q1)
    uint2 rr[2][4];
    if (bfm) {
      #pragma unroll
      for (int qt = 0; qt < 2; ++qt)
        #pragma unroll
        for (int mt = 0; mt < 4; ++mt)
          rr[qt][mt] = *(const uint2*)(relh + rbase + (size_t)qt*16384 + t*64 + mt*16 + lg*4);
    } else {
      #pragma unroll
      for (int qt = 0; qt < 2; ++qt)
        #pragma unroll
        for (int mt = 0; mt < 4; ++mt) {
          float4 q_ = *(const float4*)(relf + rbase + (size_t)qt*16384 + t*64 + mt*16 + lg*4);
          rr[qt][mt].x = pkcvt(q_.x, q_.y); rr[qt][mt].y = pkcvt(q_.z, q_.w);
        }
    }

    // async staging: V(t) and K(t+1)
    gld_lds16(vt + vg1 + t*64, &Vbuf[jv1*512]);
    if (wave >= 2) gld_lds16(vt + vg2 + t*64, &Vbuf[jv2*512]);
    const int T = (t + 1 < 16) ? t + 1 : 15;
    gld_lds16(kb + kbase + (size_t)T*24576 + (size_t)lane*384 + jk1*8, &Kbuf[nbuf][jk1*512]);
    if (wave < 2) gld_lds16(kb + kbase + (size_t)T*24576 + (size_t)lane*384 + jk2*8, &Kbuf[nbuf][jk2*512]);

    // ---- S-phase qt0: 8 MFMAs ----
    f32x4 s0[4];
    #pragma unroll
    for (int mt = 0; mt < 4; ++mt) {
      bf16x8 k0 = *(const bf16x8*)&Kbuf[cbuf][lg*512 + (mt*16 + ln)*8];
      bf16x8 k1 = {0,0,0,0,0,0,0,0};
      if (lg < 2) k1 = *(const bf16x8*)&Kbuf[cbuf][(4 + lg)*512 + (mt*16 + ln)*8];
      s0[mt] = __builtin_amdgcn_mfma_f32_16x16x32_bf16(k0, qf0[0], (f32x4){0.f,0.f,0.f,0.f}, 0, 0, 0);
      s0[mt] = __builtin_amdgcn_mfma_f32_16x16x32_bf16(k1, qf1[0], s0[mt], 0, 0, 0);
    }
    // ---- softmax qt0 -> Ps (swizzled) ----
    {
      float lacc = 0.f;
      #pragma unroll
      for (int mt = 0; mt < 4; ++mt) {
        float r0 = bf_lo(rr[0][mt].x), r1 = bf_hi(rr[0][mt].x);
        float r2 = bf_lo(rr[0][mt].y), r3 = bf_hi(rr[0][mt].y);
        float p0 = fast_exp2(fmaf(s0[mt][0], SCL, r0 * LOG2E));
        float p1 = fast_exp2(fmaf(s0[mt][1], SCL, r1 * LOG2E));
        float p2 = fast_exp2(fmaf(s0[mt][2], SCL, r2 * LOG2E));
        float p3 = fast_exp2(fmaf(s0[mt][3], SCL, r3 * LOG2E));
        lacc += (p0 + p1) + (p2 + p3);
        uint2 w; w.x = pkcvt(p0, p1); w.y = pkcvt(p2, p3);
        *(uint2*)(psrow + (((unsigned)(mt*32 + lg*8)) ^ swz)) = w;
      }
      lsum[0] += lacc;
    }

    __syncthreads();     // B: vmcnt(0) drain -> V(t)/K(t+1) in LDS (covered by S0+sm0)

    // ---- PV qt0: 6 MFMAs ----
    #pragma unroll
    for (int ks = 0; ks < 2; ++ks) {
      bf16x8 vf[3];
      #pragma unroll
      for (int nd = 0; nd < 3; ++nd)
        vf[nd] = *(const bf16x8*)&Vbuf[(ks*4 + lg)*384 + (nd*16 + ln)*8];
      bf16x8 pa = *(const bf16x8*)(psrow + (((unsigned)(ks*64 + lg*16)) ^ swz));
      #pragma unroll
      for (int nd = 0; nd < 3; ++nd)
        o[0][nd] = __builtin_amdgcn_mfma_f32_16x16x32_bf16(pa, vf[nd], o[0][nd], 0, 0, 0);
    }

    // ---- S-phase qt1: 8 MFMAs (Kbuf[cbuf] still valid) ----
    f32x4 s1[4];
    #pragma unroll
    for (int mt = 0; mt < 4; ++mt) {
      bf16x8 k0 = *(const bf16x8*)&Kbuf[cbuf][lg*512 + (mt*16 + ln)*8];
      bf16x8 k1 = {0,0,0,0,0,0,0,0};
      if (lg < 2) k1 = *(const bf16x8*)&Kbuf[cbuf][(4 + lg)*512 + (mt*16 + ln)*8];
      s1[mt] = __builtin_amdgcn_mfma_f32_16x16x32_bf16(k0, qf0[1], (f32x4){0.f,0.f,0.f,0.f}, 0, 0, 0);
      s1[mt] = __builtin_amdgcn_mfma_f32_16x16x32_bf16(k1, qf1[1], s1[mt], 0, 0, 0);
    }
    // ---- softmax qt1 -> Ps (reuse; in-order per-wave DS makes this safe) ----
    {
      float lacc = 0.f;
      #pragma unroll
      for (int mt = 0; mt < 4; ++mt) {
        float r0 = bf_lo(rr[1][mt].x), r1 = bf_hi(rr[1][mt].x);
        float r2 = bf_lo(rr[1][mt].y), r3 = bf_hi(rr[1][mt].y);
        float p0 = fast_exp2(fmaf(s1[mt][0], SCL, r0 * LOG2E));
        float p1 = fast_exp2(fmaf(s1[mt][1], SCL, r1 * LOG2E));
        float p2 = fast_exp2(fmaf(s1[mt][2], SCL, r2 * LOG2E));
        float p3 = fast_exp2(fmaf(s1[mt][3], SCL, r3 * LOG2E));
        lacc += (p0 + p1) + (p2 + p3);
        uint2 w; w.x = pkcvt(p0, p1); w.y = pkcvt(p2, p3);
        *(uint2*)(psrow + (((unsigned)(mt*32 + lg*8)) ^ swz)) = w;
      }
      lsum[1] += lacc;
    }
    // ---- PV qt1: 6 MFMAs ----
    #pragma unroll
    for (int ks = 0; ks < 2; ++ks) {
      bf16x8 vf[3];
      #pragma unroll
      for (int nd = 0; nd < 3; ++nd)
        vf[nd] = *(const bf16x8*)&Vbuf[(ks*4 + lg)*384 + (nd*16 + ln)*8];
      bf16x8 pa = *(const bf16x8*)(psrow + (((unsigned)(ks*64 + lg*16)) ^ swz));
      #pragma unroll
      for (int nd = 0; nd < 3; ++nd)
        o[1][nd] = __builtin_amdgcn_mfma_f32_16x16x32_bf16(pa, vf[nd], o[1][nd], 0, 0, 0);
    }
  }

  // l: reduce across the 4 lg-lanes of each q-row; transpose via Ls
  #pragma unroll
  for (int qt = 0; qt < 2; ++qt) {
    lsum[qt] += __shfl_xor(lsum[qt], 16, 64);
    lsum[qt] += __shfl_xor(lsum[qt], 32, 64);
    if (lg == 0) Ls[wave][qt*16 + ln] = lsum[qt];
  }
  #pragma unroll
  for (int qt = 0; qt < 2; ++qt)
    #pragma unroll
    for (int r = 0; r < 4; ++r) {
      float l = Ls[wave][qt*16 + lg*4 + r];
      float linv = 1.0f / l;
      size_t rowb = ((size_t)(b*4096 + qrow0 + qt*16 + lg*4 + r))*384 + h*48 + ln;
      #pragma unroll
      for (int nd = 0; nd < 3; ++nd)
        ob[rowb + nd*16] = f2bf(o[qt][nd][r] * linv);
    }
}

extern "C" void kernel_launch(void* const* d_in, const int* in_sizes, int n_in,
                              void* d_out, int out_size, void* d_ws, size_t ws_size,
                              hipStream_t stream) {
  // d_in: 0=x 1=relative_pos 2=H 3=W 4=Wq 5=Wk 6=Wv 7=Wp 8=bp 9=sr_w 10=sr_b
  //       11=bn_gamma 12=bn_beta 13=bn_mean 14=bn_var
  float* ws = (float*)d_ws;
  int* flag = (int*)d_ws;
  unsigned short* u = (unsigned short*)d_ws;

  detect_bf16<<<1, 64, 0, stream>>>((const unsigned*)d_in[0], flag);
  convert_all<<<3363, 256, 0, stream>>>(d_in[0], d_in[4], d_in[5], d_in[6], d_in[7],
      d_in[8], d_in[9], d_in[10], d_in[11], d_in[12], d_in[13], d_in[14], ws);
  sr_bn<<<768, 256, 0, stream>>>(u + U_XB, ws, u + U_XK);
  proj_qkv<<<dim3(3, 192), 512, 0, stream>>>(u);
  attn_mfma<<<dim3(128, 8), 256, 0, stream>>>(u + U_QB, u + U_KB, u + U_VT, d_in[1], flag, u + U_OB);
  gemm_out<<<dim3(3, 128), 512, 0, stream>>>(u + U_OB, u + U_WP, ws + OFF_BPf, d_out, flag);
}